// Round 3
// baseline (899.825 us; speedup 1.0000x reference)
//
#include <hip/hip_runtime.h>

// ReLU-RNN B=8192, T=1024, I=7, H=100, O=1 — barrier-free MFMA recurrence.
//
// v4: 2 WAVES PER SIMD. Busy-time accounting across v1/v2/v3 shows a lone
// wave pays ~16-17 cy per MFMA (issue latency) vs the 4.85 cy pipe rate,
// and cannot overlap its own VALU with its own MFMA — per-step time ==
// MFMA_busy + VALU_busy, serialized. Fix: 64 blocks x 512 threads; the 8
// waves of a block round-robin onto the 4 SIMDs -> 2 co-resident waves per
// SIMD whose streams interleave (MFMA of one fills VALU/issue gaps of the
// other). Each wave owns an independent 16-row tile; no barriers, no LDS.
//
// Also fixes v3's regression: the refill dwordx4 is stored RAW (f32x4) and
// the q1 component-select happens at CONSUMPTION (4 steps later), so the
// vmcnt wait lands where the load is long retired — v3 selected right
// after the load and exposed ~200cy of memory latency per step.
//
// Permuted-index scheme unchanged:
//   D position (ti, q, r) [n' = 16ti+4q+r, batch m = lane&15] maps to
//   B slot k' = 32kt + 8q + jj ; kt=3,jj>=4 slots carry x0..x6 and bias.

typedef _Float16 half8 __attribute__((ext_vector_type(8)));
typedef float f32x4 __attribute__((ext_vector_type(4)));
typedef unsigned u32x4 __attribute__((ext_vector_type(4)));

static __device__ __forceinline__ unsigned pkrtz(float a, float b) {
    return __builtin_bit_cast(unsigned, __builtin_amdgcn_cvt_pkrtz(a, b));
}

// 4-byte-aligned float4 load (x rows have stride 7 floats; t*7 is odd-dword)
static __device__ __forceinline__ f32x4 ld4(const float* p) {
    typedef f32x4 __attribute__((aligned(4))) f32x4a;
    return *(const f32x4a*)p;
}

__global__ __launch_bounds__(512, 1)
void rnn_wave(const float* __restrict__ x,
              const float* __restrict__ W_ih,
              const float* __restrict__ W_hh,
              const float* __restrict__ b_ih,
              const float* __restrict__ b_hh,
              const float* __restrict__ W_fc,
              const float* __restrict__ b_fc,
              float* __restrict__ out) {
    const int l  = threadIdx.x & 63;   // lane within wave
    const int wv = threadIdx.x >> 6;   // wave id 0..7 -> SIMD wv&3 (2 waves/SIMD)
    const int tile = blockIdx.x * 8 + wv;   // independent 16-row batch tile
    const int lm = l & 15;           // batch row within tile
    const int q  = l >> 4;           // quad
    const bool q1 = (q == 1);

    // ---- W' fragments (constant for all 1024 steps; 7 tiles x 4 kt) ----
    half8 w[7][4];
#pragma unroll
    for (int ti = 0; ti < 7; ++ti) {
        const int np = 16 * ti + lm;                  // output row n'
#pragma unroll
        for (int kt = 0; kt < 4; ++kt) {
            half8 hw;
#pragma unroll
            for (int jj = 0; jj < 8; ++jj) {
                float v = 0.f;
                if (np < 100) {
                    if (jj < 4) {                     // h slot, p = 16kt+4q+jj
                        int p = 16 * kt + 4 * q + jj;
                        if (p < 100) v = W_hh[np * 100 + p];
                    } else if (kt < 3) {              // h slot, p = 16(kt+4)+4q+(jj-4)
                        int p = 16 * (kt + 4) + 4 * q + (jj - 4);
                        if (p < 100) v = W_hh[np * 100 + p];
                    } else {                          // kt==3, jj>=4: x / bias slots
                        if (q == 0)      v = W_ih[np * 7 + (jj - 4)];      // x0..x3
                        else if (q == 1) v = (jj < 7) ? W_ih[np * 7 + jj]  // x4..x6
                                             : (b_ih[np] + b_hh[np]);     // bias @ jj=7
                        // q>=2: stays 0 — their hf[3] tail is don't-care
                    }
                }
                hw[jj] = (_Float16)v;
            }
            w[ti][kt] = hw;
        }
    }

    // ---- x addressing: one raw dwordx4 per step per lane ----
    const float* xr = x + (size_t)(tile * 16 + lm) * 7168;
    const int xo = q1 ? 3 : 0;       // q1 reads (x3,x4,x5,x6); others (x0..x3)

    const u32x4 zz = {0u, 0u, 0u, 0u};
    const half8 hz = __builtin_bit_cast(half8, zz);

    // hfrag for t=0: h=0 everywhere, x_0/bias in kt=3 tail
    half8 hf[4];
    {
        f32x4 v = ld4(xr + xo);
        float x0 = q1 ? v.y : v.x, x1 = q1 ? v.z : v.y;
        float x2 = q1 ? v.w : v.z, x3 = q1 ? 1.0f : v.w;
        hf[0] = hz; hf[1] = hz; hf[2] = hz;
        u32x4 h3 = {0u, 0u, pkrtz(x0, x1), pkrtz(x2, x3)};
        hf[3] = __builtin_bit_cast(half8, h3);
    }

    // depth-4 x prefetch: slot s&3 holds the RAW dwordx4 of x_s.
    // Component select is deferred to consumption (keeps vmcnt waits off
    // the load; the load retires during the intervening 4 steps).
    f32x4 xv[4];
#pragma unroll
    for (int s = 1; s <= 4; ++s) xv[s & 3] = ld4(xr + s * 7 + xo);

    const f32x4 kZ = {0.f, 0.f, 0.f, 0.f};
    f32x4 acc[7];

    for (int tb = 0; tb < 1024; tb += 4) {
#pragma unroll
        for (int u = 0; u < 4; ++u) {
            const int t = tb + u;

            // 28 MFMAs; chains spaced 7 apart. Order {0,4,1,5,2,6,3} so the
            // chains feeding hf[0] (acc0/acc4) retire earliest.
#pragma unroll
            for (int kt = 0; kt < 4; ++kt) {
                const int order[7] = {0, 4, 1, 5, 2, 6, 3};
#pragma unroll
                for (int oi = 0; oi < 7; ++oi) {
                    const int ti = order[oi];
                    acc[ti] = __builtin_amdgcn_mfma_f32_16x16x32_f16(
                        w[ti][kt], hf[kt], (kt == 0) ? kZ : acc[ti], 0, 0, 0);
                }
            }

            // in-register repack: D -> next B fragment (pack, then packed relu)
            const int s = (u + 1) & 3;
#pragma unroll
            for (int kt = 0; kt < 3; ++kt) {
                u32x4 d;
                d.x = pkrtz(acc[kt][0],     acc[kt][1]);
                d.y = pkrtz(acc[kt][2],     acc[kt][3]);
                d.z = pkrtz(acc[kt + 4][0], acc[kt + 4][1]);
                d.w = pkrtz(acc[kt + 4][2], acc[kt + 4][3]);
                hf[kt] = __builtin_elementwise_max(__builtin_bit_cast(half8, d), hz);
            }
            {
                // kt=3: h part needs relu; x/bias words pass through raw.
                // q-select happens HERE (consumption), 4 steps after the load.
                f32x4 v = xv[s];
                float a = q1 ? v.y : v.x, b = q1 ? v.z : v.y;
                float c = q1 ? v.w : v.z, e = q1 ? 1.0f : v.w;
                u32x4 d;
                d.x = pkrtz(fmaxf(acc[3][0], 0.f), fmaxf(acc[3][1], 0.f));
                d.y = pkrtz(fmaxf(acc[3][2], 0.f), fmaxf(acc[3][3], 0.f));
                d.z = pkrtz(a, b);
                d.w = pkrtz(c, e);
                hf[3] = __builtin_bit_cast(half8, d);
            }

            // refill slot s with x_{t+5} raw (used 4 steps from now)
            int tn = t + 5; if (tn > 1023) tn = 1023;
            xv[s] = ld4(xr + tn * 7 + xo);
        }
    }

    // ---- epilogue: acc holds pre-relu h_T (permuted space, batch = lm) ----
    float sum = 0.f;
#pragma unroll
    for (int ti = 0; ti < 7; ++ti) {
#pragma unroll
        for (int r = 0; r < 4; ++r) {
            const int np = 16 * ti + 4 * q + r;
            const float wf = (np < 100) ? W_fc[np] : 0.f;
            sum += wf * fmaxf(acc[ti][r], 0.f);
        }
    }
    sum += __shfl_xor(sum, 16, 64);   // reduce across the 4 q-lanes of row lm
    sum += __shfl_xor(sum, 32, 64);
    if (q == 0) out[tile * 16 + lm] = sum + b_fc[0];
}

extern "C" void kernel_launch(void* const* d_in, const int* in_sizes, int n_in,
                              void* d_out, int out_size, void* d_ws, size_t ws_size,
                              hipStream_t stream) {
    const float* x    = (const float*)d_in[0];
    const float* W_ih = (const float*)d_in[1];
    const float* W_hh = (const float*)d_in[2];
    const float* b_ih = (const float*)d_in[3];
    const float* b_hh = (const float*)d_in[4];
    const float* W_fc = (const float*)d_in[5];
    const float* b_fc = (const float*)d_in[6];
    float* out = (float*)d_out;

    rnn_wave<<<dim3(64), dim3(512), 0, stream>>>(x, W_ih, W_hh, b_ih, b_hh, W_fc, b_fc, out);
}

// Round 4
// 646.958 us; speedup vs baseline: 1.3909x; 1.3909x over previous
//
#include <hip/hip_runtime.h>

// ReLU-RNN B=8192, T=1024, I=7, H=100, O=1 — barrier-free MFMA recurrence.
//
// v5: ROTATED + INTERLEAVED loop. Measured model (v1-v4): 16x16x32 f16 MFMA
// costs 19.4 cy/SIMD (m06 recomputed per-SIMD: 844 FLOP/cy), so the 28
// MFMAs/step are a 543 cy pipe floor; v3's extra ~530 cy was the repack
// VALU serialized AFTER the MFMA block (it read the kt=3 accs, so nothing
// was independent) plus stalls. Fix: rotate the loop so the body starts by
// repacking the PREVIOUS step's acc into hf, and embed the hf[1..3] repacks
// between the kt0 MFMAs (kt-block b only reads hf[b]). In-order wave issue
// then slots VALU into the MFMA pipe-occupancy gaps. acc=0 init makes the
// rotated first iteration produce the t=0 state (relu-pack(0)=0 + x_0).
// sched_group_barrier pins the MFMA/VALU interleave template.
//
// Grid 512x64: 1 wave/SIMD across 512 SIMDs (v4 proved 2 waves/SIMD just
// queue on the MFMA pipe; SIMD spread is what matters).
//
// Permuted-index scheme unchanged:
//   D position (ti, q, r) [n' = 16ti+4q+r, batch m = lane&15] maps to
//   B slot k' = 32kt + 8q + jj ; kt=3,jj>=4 slots carry x0..x6 and bias.

typedef _Float16 half8 __attribute__((ext_vector_type(8)));
typedef float f32x4 __attribute__((ext_vector_type(4)));
typedef unsigned u32x4 __attribute__((ext_vector_type(4)));

static __device__ __forceinline__ unsigned pkrtz(float a, float b) {
    return __builtin_bit_cast(unsigned, __builtin_amdgcn_cvt_pkrtz(a, b));
}

// 4-byte-aligned float4 load (x rows have stride 7 floats; t*7 is odd-dword)
static __device__ __forceinline__ f32x4 ld4(const float* p) {
    typedef f32x4 __attribute__((aligned(4))) f32x4a;
    return *(const f32x4a*)p;
}

// sched_group_barrier masks: VALU=0x2, MFMA=0x8, VMEM_READ=0x20
#define SGB(mask, n) __builtin_amdgcn_sched_group_barrier(mask, n, 0)

__global__ __launch_bounds__(64, 1)
void rnn_wave(const float* __restrict__ x,
              const float* __restrict__ W_ih,
              const float* __restrict__ W_hh,
              const float* __restrict__ b_ih,
              const float* __restrict__ b_hh,
              const float* __restrict__ W_fc,
              const float* __restrict__ b_fc,
              float* __restrict__ out) {
    const int l  = threadIdx.x;
    const int lm = l & 15;           // batch row within tile
    const int q  = l >> 4;           // quad
    const bool q1 = (q == 1);

    // ---- W' fragments (constant for all 1024 steps; 7 tiles x 4 kt) ----
    half8 w[7][4];
#pragma unroll
    for (int ti = 0; ti < 7; ++ti) {
        const int np = 16 * ti + lm;                  // output row n'
#pragma unroll
        for (int kt = 0; kt < 4; ++kt) {
            half8 hw;
#pragma unroll
            for (int jj = 0; jj < 8; ++jj) {
                float v = 0.f;
                if (np < 100) {
                    if (jj < 4) {                     // h slot, p = 16kt+4q+jj
                        int p = 16 * kt + 4 * q + jj;
                        if (p < 100) v = W_hh[np * 100 + p];
                    } else if (kt < 3) {              // h slot, p = 16(kt+4)+4q+(jj-4)
                        int p = 16 * (kt + 4) + 4 * q + (jj - 4);
                        if (p < 100) v = W_hh[np * 100 + p];
                    } else {                          // kt==3, jj>=4: x / bias slots
                        if (q == 0)      v = W_ih[np * 7 + (jj - 4)];      // x0..x3
                        else if (q == 1) v = (jj < 7) ? W_ih[np * 7 + jj]  // x4..x6
                                             : (b_ih[np] + b_hh[np]);     // bias @ jj=7
                        // q>=2: stays 0 — their hf[3] tail is don't-care
                    }
                }
                hw[jj] = (_Float16)v;
            }
            w[ti][kt] = hw;
        }
    }

    // ---- x addressing: one raw dwordx4 per step per lane ----
    const float* xr = x + (size_t)(blockIdx.x * 16 + lm) * 7168;
    const int xo = q1 ? 3 : 0;       // q1 reads (x3,x4,x5,x6); others (x0..x3)

    const u32x4 zz = {0u, 0u, 0u, 0u};
    const half8 hz = __builtin_bit_cast(half8, zz);

    // depth-4 x prefetch ring: slot t&3 holds RAW dwordx4 of x_t.
    // Component select deferred to consumption (4 steps after the load).
    f32x4 xv[4];
#pragma unroll
    for (int s = 0; s < 4; ++s) xv[s] = ld4(xr + s * 7 + xo);

    const f32x4 kZ = {0.f, 0.f, 0.f, 0.f};
    f32x4 acc[7];
#pragma unroll
    for (int i = 0; i < 7; ++i) acc[i] = kZ;   // rotated t=0: repack(0)=0 = h_0
    half8 hf[4];

    for (int tb = 0; tb < 1024; tb += 4) {
#pragma unroll
        for (int u = 0; u < 4; ++u) {
            const int t = tb + u;

            // ---- hf0 <- relu-pack(prev acc0, acc4) ----
            {
                u32x4 d;
                d.x = pkrtz(acc[0][0], acc[0][1]);
                d.y = pkrtz(acc[0][2], acc[0][3]);
                d.z = pkrtz(acc[4][0], acc[4][1]);
                d.w = pkrtz(acc[4][2], acc[4][3]);
                hf[0] = __builtin_elementwise_max(__builtin_bit_cast(half8, d), hz);
            }
            SGB(0x2, 8);
            // ---- kt0 with embedded repacks (kt0 reads only hf[0]) ----
            acc[0] = __builtin_amdgcn_mfma_f32_16x16x32_f16(w[0][0], hf[0], kZ, 0, 0, 0);
            acc[4] = __builtin_amdgcn_mfma_f32_16x16x32_f16(w[4][0], hf[0], kZ, 0, 0, 0);
            SGB(0x8, 2);
            {
                u32x4 d;
                d.x = pkrtz(acc[1][0], acc[1][1]);
                d.y = pkrtz(acc[1][2], acc[1][3]);
                d.z = pkrtz(acc[5][0], acc[5][1]);
                d.w = pkrtz(acc[5][2], acc[5][3]);
                hf[1] = __builtin_elementwise_max(__builtin_bit_cast(half8, d), hz);
            }
            SGB(0x2, 8);
            acc[1] = __builtin_amdgcn_mfma_f32_16x16x32_f16(w[1][0], hf[0], kZ, 0, 0, 0);
            acc[5] = __builtin_amdgcn_mfma_f32_16x16x32_f16(w[5][0], hf[0], kZ, 0, 0, 0);
            SGB(0x8, 2);
            {
                u32x4 d;
                d.x = pkrtz(acc[2][0], acc[2][1]);
                d.y = pkrtz(acc[2][2], acc[2][3]);
                d.z = pkrtz(acc[6][0], acc[6][1]);
                d.w = pkrtz(acc[6][2], acc[6][3]);
                hf[2] = __builtin_elementwise_max(__builtin_bit_cast(half8, d), hz);
            }
            SGB(0x2, 8);
            acc[2] = __builtin_amdgcn_mfma_f32_16x16x32_f16(w[2][0], hf[0], kZ, 0, 0, 0);
            acc[6] = __builtin_amdgcn_mfma_f32_16x16x32_f16(w[6][0], hf[0], kZ, 0, 0, 0);
            SGB(0x8, 2);
            {
                // hf3: relu'd h part (prev acc3) + raw x_t/bias words
                f32x4 v = xv[u];
                float a_ = q1 ? v.y : v.x, b_ = q1 ? v.z : v.y;
                float c_ = q1 ? v.w : v.z, e_ = q1 ? 1.0f : v.w;
                u32x4 d;
                d.x = pkrtz(fmaxf(acc[3][0], 0.f), fmaxf(acc[3][1], 0.f));
                d.y = pkrtz(fmaxf(acc[3][2], 0.f), fmaxf(acc[3][3], 0.f));
                d.z = pkrtz(a_, b_);
                d.w = pkrtz(c_, e_);
                hf[3] = __builtin_bit_cast(half8, d);
            }
            SGB(0x2, 12);
            acc[3] = __builtin_amdgcn_mfma_f32_16x16x32_f16(w[3][0], hf[0], kZ, 0, 0, 0);
            SGB(0x8, 1);

            // ---- kt1 (reads hf[1]); x refill issued inside ----
            acc[0] = __builtin_amdgcn_mfma_f32_16x16x32_f16(w[0][1], hf[1], acc[0], 0, 0, 0);
            acc[1] = __builtin_amdgcn_mfma_f32_16x16x32_f16(w[1][1], hf[1], acc[1], 0, 0, 0);
            SGB(0x8, 2);
            {
                int tn = t + 4; if (tn > 1023) tn = 1023;
                xv[u] = ld4(xr + tn * 7 + xo);     // consumed at iter t+4
            }
            SGB(0x20, 1);
            acc[2] = __builtin_amdgcn_mfma_f32_16x16x32_f16(w[2][1], hf[1], acc[2], 0, 0, 0);
            acc[3] = __builtin_amdgcn_mfma_f32_16x16x32_f16(w[3][1], hf[1], acc[3], 0, 0, 0);
            acc[4] = __builtin_amdgcn_mfma_f32_16x16x32_f16(w[4][1], hf[1], acc[4], 0, 0, 0);
            acc[5] = __builtin_amdgcn_mfma_f32_16x16x32_f16(w[5][1], hf[1], acc[5], 0, 0, 0);
            acc[6] = __builtin_amdgcn_mfma_f32_16x16x32_f16(w[6][1], hf[1], acc[6], 0, 0, 0);
            SGB(0x8, 5);

            // ---- kt2 (reads hf[2]) ----
#pragma unroll
            for (int ti = 0; ti < 7; ++ti)
                acc[ti] = __builtin_amdgcn_mfma_f32_16x16x32_f16(w[ti][2], hf[2], acc[ti], 0, 0, 0);
            SGB(0x8, 7);

            // ---- kt3 (reads hf[3]); order {0,4,...} so acc0/acc4 retire first
            {
                const int order[7] = {0, 4, 1, 5, 2, 6, 3};
#pragma unroll
                for (int oi = 0; oi < 7; ++oi) {
                    const int ti = order[oi];
                    acc[ti] = __builtin_amdgcn_mfma_f32_16x16x32_f16(w[ti][3], hf[3], acc[ti], 0, 0, 0);
                }
            }
            SGB(0x8, 7);
        }
    }

    // ---- epilogue: acc holds pre-relu h_T (permuted space, batch = lm) ----
    float sum = 0.f;
#pragma unroll
    for (int ti = 0; ti < 7; ++ti) {
#pragma unroll
        for (int r = 0; r < 4; ++r) {
            const int np = 16 * ti + 4 * q + r;
            const float wf = (np < 100) ? W_fc[np] : 0.f;
            sum += wf * fmaxf(acc[ti][r], 0.f);
        }
    }
    sum += __shfl_xor(sum, 16, 64);   // reduce across the 4 q-lanes of row lm
    sum += __shfl_xor(sum, 32, 64);
    if (q == 0) out[blockIdx.x * 16 + lm] = sum + b_fc[0];
}

extern "C" void kernel_launch(void* const* d_in, const int* in_sizes, int n_in,
                              void* d_out, int out_size, void* d_ws, size_t ws_size,
                              hipStream_t stream) {
    const float* x    = (const float*)d_in[0];
    const float* W_ih = (const float*)d_in[1];
    const float* W_hh = (const float*)d_in[2];
    const float* b_ih = (const float*)d_in[3];
    const float* b_hh = (const float*)d_in[4];
    const float* W_fc = (const float*)d_in[5];
    const float* b_fc = (const float*)d_in[6];
    float* out = (float*)d_out;

    rnn_wave<<<dim3(512), dim3(64), 0, stream>>>(x, W_ih, W_hh, b_ih, b_hh, W_fc, b_fc, out);
}